// Round 10
// baseline (91.799 us; speedup 1.0000x reference)
//
#include <hip/hip_runtime.h>
#include <hip/hip_cooperative_groups.h>

// T_lv2: out[0..4718591]        = fold(gather(unfold(ref_lv2,3,1,1)))/9  [4,128,96,96]
// T_lv1: out[4718592..9437183]  = fold(gather(unfold(ref_lv1,6,2,2)))/9  [4,64,192,192]
//
// R9 = R6 (best: 28.1us) with the table kernel FUSED via cooperative launch:
//   [table-build (1 entry/thread, blocks 0..71) || LDS stage] -> grid.sync()
//   -> R6 gather (byte-identical).
// Tap table: tabA[b][u]=uint4 (taps 0..7 as 8xu16 cell idx), tabB=tap 8.
// bf16 4-value 8B cells, random ds_read_b64; 512 blocks x 512 thr, 73.75KB
// LDS -> exactly 2 blocks/CU (grid == resident capacity, coop-legal).
// Breadth-first dispatch pairs block c with c+256 on a CU = lv1+lv2 mix
// (phase overlap). Do NOT remap roles (R8 lesson).

namespace cg = cooperative_groups;

typedef float f2 __attribute__((ext_vector_type(2)));
typedef float f4 __attribute__((ext_vector_type(4)));

#define NINE_INV (1.0f / 9.0f)
#define ZCELL 9216u

__device__ __forceinline__ unsigned rne_bf16(float f) {
    unsigned u = __builtin_bit_cast(unsigned, f);
    return (u + 0x7fffu + ((u >> 16) & 1u)) >> 16;
}
__device__ __forceinline__ unsigned pack_bf2(float a, float b) {
    return rne_bf16(a) | (rne_bf16(b) << 16);
}
__device__ __forceinline__ f2 up2(unsigned w) {
    f2 r;
    r.x = __builtin_bit_cast(float, w << 16);
    r.y = __builtin_bit_cast(float, w & 0xffff0000u);
    return r;
}
template <typename T> __device__ __forceinline__ T ntload(const T* p) {
    return __builtin_nontemporal_load(p);
}
template <typename T> __device__ __forceinline__ void ntstore(T* p, T v) {
    __builtin_nontemporal_store(v, p);
}

// Build one packed tap-table entry (position g = b*9216+u).
__device__ __forceinline__ void build_entry(const int* __restrict__ idx, int g,
                                            uint4* __restrict__ tabA,
                                            unsigned short* __restrict__ tabB)
{
    int b = g / 9216;
    int u = g - b * 9216;
    const int* idxb = idx + b * 9216;
    int r = u / 96, t = u - 96 * r;
    unsigned e[9];
#pragma unroll
    for (int i = 0; i < 3; ++i) {
        int oy = r - 1 + i;
        bool oyv = (unsigned)oy < 96u;
#pragma unroll
        for (int j = 0; j < 3; ++j) {
            int ox = t - 1 + j;
            bool pv = oyv & ((unsigned)ox < 96u);
            int jv = idxb[pv ? oy * 96 + ox : 0];
            int jy = jv / 96, jx = jv - 96 * jy;
            int ysh = jy + 1 - i, xsh = jx + 1 - j;
            bool sv = pv & ((unsigned)ysh < 96u) & ((unsigned)xsh < 96u);
            e[i * 3 + j] = sv ? (unsigned)(ysh * 96 + xsh) : ZCELL;
        }
    }
    uint4 w;
    w.x = e[0] | (e[1] << 16);
    w.y = e[2] | (e[3] << 16);
    w.z = e[4] | (e[5] << 16);
    w.w = e[6] | (e[7] << 16);
    tabA[g] = w;
    tabB[g] = (unsigned short)e[8];
}

__global__ __launch_bounds__(512, 4) void transfer_coop(
    const int* __restrict__ idx,      // [4, 9216]
    const float* __restrict__ ref1,   // [4,64,192,192]
    const float* __restrict__ ref2,   // [4,128,96,96]
    uint4* __restrict__ tabA,         // [4][9216] taps 0..7
    unsigned short* __restrict__ tabB,// [4][9216] tap 8
    float* __restrict__ out)
{
    __shared__ __align__(16) unsigned s2[18436];   // 9217 cells x 2 words (+pad)
    const int tid = threadIdx.x;
    const int bid = blockIdx.x;
    const int b = bid & 3;

    if (tid < 4) s2[18432 + tid] = 0;              // zero cell (+pad)

    // ---- phase 1a: table build (1 entry/thread, first 72 blocks) ----
    {
        int g = bid * 512 + tid;
        if (g < 36864) build_entry(idx, g, tabA, tabB);
    }

    const uint4* tA = tabA + b * 9216;
    const unsigned short* tB = tabB + b * 9216;
    const f2 nv = {NINE_INV, NINE_INV};

    auto do_taps = [&](const unsigned* cw, unsigned c8, f2& a0, f2& a1) {
#pragma unroll
        for (int q = 0; q < 4; ++q) {
            unsigned lo = cw[q] & 0xffffu, hi = cw[q] >> 16;
            uint2 wa = *(const uint2*)((const char*)s2 + (lo << 3));
            uint2 wb = *(const uint2*)((const char*)s2 + (hi << 3));
            a0 += up2(wa.x); a1 += up2(wa.y);
            a0 += up2(wb.x); a1 += up2(wb.y);
        }
        uint2 wc = *(const uint2*)((const char*)s2 + (c8 << 3));
        a0 += up2(wc.x); a1 += up2(wc.y);
    };

    if (bid < 256) {
        // ---------------- lv1: b, parity q, channel pair ----------------
        const int q = (bid >> 2) & 1, c0 = (bid >> 3) * 2;
        const float* g0 = ref1 + (size_t)(b * 64 + c0) * 36864;

        // ---- phase 1b: stage (independent of table) ----
        for (int u2 = tid; u2 < 4608; u2 += 512) {
            int ysh = u2 / 48, xsh0 = 2 * (u2 - 48 * ysh);
            const float* gp = g0 + (size_t)(2 * ysh + q) * 192 + 2 * xsh0;
            f4 va = ntload((const f4*)gp);            // ch0
            f4 vb = ntload((const f4*)(gp + 36864));  // ch1
            uint4 w;
            w.x = pack_bf2(va.x, va.y); w.y = pack_bf2(vb.x, vb.y);
            w.z = pack_bf2(va.z, va.w); w.w = pack_bf2(vb.z, vb.w);
            *(uint4*)(s2 + 4 * u2) = w;
        }

        cg::this_grid().sync();   // table visible + LDS staged

        float* ob = out + 4718592 + (size_t)(b * 64 + c0) * 36864;

        uint4 cA = tA[tid]; unsigned cB = tB[tid];
        int u = tid;
#pragma unroll 2
        for (int k = 0; k < 18; ++k) {
            uint4 nA = cA; unsigned nB = cB;
            if (k < 17) { nA = tA[u + 512]; nB = tB[u + 512]; }
            unsigned cw[4];
            cw[0] = cA.x; cw[1] = cA.y; cw[2] = cA.z; cw[3] = cA.w;
            unsigned c8 = cB;
            f2 a0 = {0.f, 0.f}, a1 = {0.f, 0.f};
            do_taps(cw, c8, a0, a1);
            a0 *= nv; a1 *= nv;
            int r = u / 96, t = u - 96 * r;
            float* op = ob + (size_t)(2 * r + q) * 192 + 2 * t;
            ntstore((f2*)op, a0);
            ntstore((f2*)(op + 36864), a1);
            u += 512; cA = nA; cB = nB;
        }
    } else {
        // ---------------- lv2: b, 4-ch group, position half ----------------
        const int r2 = bid - 256;
        const int grp = (r2 >> 2) & 31, h = (r2 >> 7) & 1;
        const int c0 = grp * 4;
        const float* g0 = ref2 + (size_t)(b * 128 + c0) * 9216;

        for (int u2 = tid; u2 < 4608; u2 += 512) {
            f2 p0 = ntload((const f2*)(g0 + 2 * u2));
            f2 p1 = ntload((const f2*)(g0 + 9216 + 2 * u2));
            f2 p2 = ntload((const f2*)(g0 + 2 * 9216 + 2 * u2));
            f2 p3 = ntload((const f2*)(g0 + 3 * 9216 + 2 * u2));
            uint4 w;
            w.x = pack_bf2(p0.x, p1.x); w.y = pack_bf2(p2.x, p3.x);
            w.z = pack_bf2(p0.y, p1.y); w.w = pack_bf2(p2.y, p3.y);
            *(uint4*)(s2 + 4 * u2) = w;
        }

        cg::this_grid().sync();

        float* ob = out + (size_t)(b * 128 + c0) * 9216;

        const int u0 = h * 4608;
        uint4 cA = tA[u0 + tid]; unsigned cB = tB[u0 + tid];
        int u = u0 + tid;
#pragma unroll 2
        for (int k = 0; k < 9; ++k) {
            uint4 nA = cA; unsigned nB = cB;
            if (k < 8) { nA = tA[u + 512]; nB = tB[u + 512]; }
            unsigned cw[4];
            cw[0] = cA.x; cw[1] = cA.y; cw[2] = cA.z; cw[3] = cA.w;
            unsigned c8 = cB;
            f2 a0 = {0.f, 0.f}, a1 = {0.f, 0.f};
            do_taps(cw, c8, a0, a1);
            a0 *= nv; a1 *= nv;
            float* op = ob + u;
            ntstore(op, a0.x);            ntstore(op + 9216, a0.y);
            ntstore(op + 2 * 9216, a1.x); ntstore(op + 3 * 9216, a1.y);
            u += 512; cA = nA; cB = nB;
        }
    }
}

// Fallback (no workspace): compute cells inline, single regular launch.
__global__ __launch_bounds__(512, 4) void transfer_fallback(
    const int* __restrict__ idx,
    const float* __restrict__ ref1,
    const float* __restrict__ ref2,
    float* __restrict__ out)
{
    __shared__ __align__(16) unsigned s2[18436];
    const int tid = threadIdx.x;
    const int bid = blockIdx.x;
    const int b = bid & 3;

    if (tid < 4) s2[18432 + tid] = 0;

    const int* idxb = idx + b * 9216;
    const f2 nv = {NINE_INV, NINE_INV};

    auto inline_cells = [&](int u, unsigned* e) {
        int r = u / 96, t = u - 96 * r;
#pragma unroll
        for (int i = 0; i < 3; ++i) {
            int oy = r - 1 + i;
            bool oyv = (unsigned)oy < 96u;
#pragma unroll
            for (int j = 0; j < 3; ++j) {
                int ox = t - 1 + j;
                bool pv = oyv & ((unsigned)ox < 96u);
                int jv = idxb[pv ? oy * 96 + ox : 0];
                int jy = jv / 96, jx = jv - 96 * jy;
                int ysh = jy + 1 - i, xsh = jx + 1 - j;
                bool sv = pv & ((unsigned)ysh < 96u) & ((unsigned)xsh < 96u);
                e[i * 3 + j] = sv ? (unsigned)(ysh * 96 + xsh) : ZCELL;
            }
        }
    };
    auto do_taps9 = [&](const unsigned* e, f2& a0, f2& a1) {
#pragma unroll
        for (int p = 0; p < 9; ++p) {
            uint2 w = *(const uint2*)((const char*)s2 + (e[p] << 3));
            a0 += up2(w.x); a1 += up2(w.y);
        }
    };

    if (bid < 256) {
        const int q = (bid >> 2) & 1, c0 = (bid >> 3) * 2;
        const float* g0 = ref1 + (size_t)(b * 64 + c0) * 36864;
        for (int u2 = tid; u2 < 4608; u2 += 512) {
            int ysh = u2 / 48, xsh0 = 2 * (u2 - 48 * ysh);
            const float* gp = g0 + (size_t)(2 * ysh + q) * 192 + 2 * xsh0;
            f4 va = ntload((const f4*)gp);
            f4 vb = ntload((const f4*)(gp + 36864));
            uint4 w;
            w.x = pack_bf2(va.x, va.y); w.y = pack_bf2(vb.x, vb.y);
            w.z = pack_bf2(va.z, va.w); w.w = pack_bf2(vb.z, vb.w);
            *(uint4*)(s2 + 4 * u2) = w;
        }
        __syncthreads();
        float* ob = out + 4718592 + (size_t)(b * 64 + c0) * 36864;
        for (int u = tid; u < 9216; u += 512) {
            unsigned e[9];
            inline_cells(u, e);
            f2 a0 = {0.f, 0.f}, a1 = {0.f, 0.f};
            do_taps9(e, a0, a1);
            a0 *= nv; a1 *= nv;
            int r = u / 96, t = u - 96 * r;
            float* op = ob + (size_t)(2 * r + q) * 192 + 2 * t;
            ntstore((f2*)op, a0);
            ntstore((f2*)(op + 36864), a1);
        }
    } else {
        const int r2 = bid - 256;
        const int grp = (r2 >> 2) & 31, h = (r2 >> 7) & 1;
        const int c0 = grp * 4;
        const float* g0 = ref2 + (size_t)(b * 128 + c0) * 9216;
        for (int u2 = tid; u2 < 4608; u2 += 512) {
            f2 p0 = ntload((const f2*)(g0 + 2 * u2));
            f2 p1 = ntload((const f2*)(g0 + 9216 + 2 * u2));
            f2 p2 = ntload((const f2*)(g0 + 2 * 9216 + 2 * u2));
            f2 p3 = ntload((const f2*)(g0 + 3 * 9216 + 2 * u2));
            uint4 w;
            w.x = pack_bf2(p0.x, p1.x); w.y = pack_bf2(p2.x, p3.x);
            w.z = pack_bf2(p0.y, p1.y); w.w = pack_bf2(p2.y, p3.y);
            *(uint4*)(s2 + 4 * u2) = w;
        }
        __syncthreads();
        float* ob = out + (size_t)(b * 128 + c0) * 9216;
        const int u0 = h * 4608;
        for (int u = u0 + tid; u < u0 + 4608; u += 512) {
            unsigned e[9];
            inline_cells(u, e);
            f2 a0 = {0.f, 0.f}, a1 = {0.f, 0.f};
            do_taps9(e, a0, a1);
            a0 *= nv; a1 *= nv;
            float* op = ob + u;
            ntstore(op, a0.x);            ntstore(op + 9216, a0.y);
            ntstore(op + 2 * 9216, a1.x); ntstore(op + 3 * 9216, a1.y);
        }
    }
}

extern "C" void kernel_launch(void* const* d_in, const int* in_sizes, int n_in,
                              void* d_out, int out_size, void* d_ws, size_t ws_size,
                              hipStream_t stream) {
    const int*   idx  = (const int*)d_in[0];   // R_lv2_star_arg [4,9216]
    const float* ref1 = (const float*)d_in[2]; // ref_lv1 [4,64,192,192]
    const float* ref2 = (const float*)d_in[3]; // ref_lv2 [4,128,96,96]
    float* outp = (float*)d_out;

    uint4* tabA = (uint4*)d_ws;                          // 4*9216*16 B
    unsigned short* tabB = (unsigned short*)((char*)d_ws + (size_t)4 * 9216 * 16);

    const size_t need = (size_t)4 * 9216 * 16 + (size_t)4 * 9216 * 2;  // 664 KB
    if (ws_size >= need) {
        void* args[] = {(void*)&idx, (void*)&ref1, (void*)&ref2,
                        (void*)&tabA, (void*)&tabB, (void*)&outp};
        hipLaunchCooperativeKernel((const void*)transfer_coop,
                                   dim3(512), dim3(512), args, 0, stream);
    } else {
        hipLaunchKernelGGL(transfer_fallback, dim3(512), dim3(512), 0, stream,
                           idx, ref1, ref2, outp);
    }
}

// Round 11
// 27.693 us; speedup vs baseline: 3.3149x; 3.3149x over previous
//
#include <hip/hip_runtime.h>

// T_lv2: out[0..4718591]         = fold(gather(unfold(ref_lv2,3,1,1)))/9  [4,128,96,96]
// T_lv1: out[4718592..14155775]  = fold(gather(unfold(ref_lv1,6,2,2)))/9  [4,64,192,192]
//
// R10 = R6 (best: 28.1us) restored byte-for-byte, with ONE change:
// staging pack uses v_cvt_pk_bf16_f32 (1 inst per packed pair, RNE) instead
// of the ~9-op manual rne_bf16 sequence. Structure untouched (R7/R8/R9
// restructures all regressed): tap table as u16 cell indices (2 coalesced
// loads/position), 1-deep prefetch, unroll 2, bf16 4-value 8B cells,
// random ds_read_b64, 512 blocks x 512 thr, 73.75KB LDS (2 blocks/CU,
// natural bid mapping -> breadth-first pairs lv1+lv2 on each CU).

typedef float f2 __attribute__((ext_vector_type(2)));
typedef float f4 __attribute__((ext_vector_type(4)));

#define NINE_INV (1.0f / 9.0f)
#define ZCELL 9216u

__device__ __forceinline__ unsigned cvt_pk_bf16(float a, float b) {
    unsigned r;
    asm("v_cvt_pk_bf16_f32 %0, %1, %2" : "=v"(r) : "v"(a), "v"(b));
    return r;   // lo16 = bf16(a), hi16 = bf16(b), RNE
}
__device__ __forceinline__ f2 up2(unsigned w) {
    f2 r;
    r.x = __builtin_bit_cast(float, w << 16);
    r.y = __builtin_bit_cast(float, w & 0xffff0000u);
    return r;
}
template <typename T> __device__ __forceinline__ T ntload(const T* p) {
    return __builtin_nontemporal_load(p);
}
template <typename T> __device__ __forceinline__ void ntstore(T* p, T v) {
    __builtin_nontemporal_store(v, p);
}

// Build the packed tap table: tabA[g] = taps 0..7 (8 x u16 cell idx), tabB[g] = tap 8.
__global__ __launch_bounds__(256) void table_kernel(
    const int* __restrict__ idx, uint4* __restrict__ tabA,
    unsigned short* __restrict__ tabB)
{
    int g = blockIdx.x * 256 + threadIdx.x;       // 0..36863
    int b = g / 9216;
    int u = g - b * 9216;
    const int* idxb = idx + b * 9216;
    int r = u / 96, t = u - 96 * r;
    unsigned e[9];
#pragma unroll
    for (int i = 0; i < 3; ++i) {
        int oy = r - 1 + i;
        bool oyv = (unsigned)oy < 96u;
#pragma unroll
        for (int j = 0; j < 3; ++j) {
            int ox = t - 1 + j;
            bool pv = oyv & ((unsigned)ox < 96u);
            int jv = idxb[pv ? oy * 96 + ox : 0];
            int jy = jv / 96, jx = jv - 96 * jy;
            int ysh = jy + 1 - i, xsh = jx + 1 - j;
            bool sv = pv & ((unsigned)ysh < 96u) & ((unsigned)xsh < 96u);
            e[i * 3 + j] = sv ? (unsigned)(ysh * 96 + xsh) : ZCELL;
        }
    }
    uint4 w;
    w.x = e[0] | (e[1] << 16);
    w.y = e[2] | (e[3] << 16);
    w.z = e[4] | (e[5] << 16);
    w.w = e[6] | (e[7] << 16);
    tabA[g] = w;
    tabB[g] = (unsigned short)e[8];
}

template <bool TAB>
__global__ __launch_bounds__(512, 4) void transfer_kernel(
    const int* __restrict__ idx,      // [4, 9216]
    const float* __restrict__ ref1,   // [4,64,192,192]
    const float* __restrict__ ref2,   // [4,128,96,96]
    const uint4* __restrict__ tabA,   // [4][9216] taps 0..7
    const unsigned short* __restrict__ tabB, // [4][9216] tap 8
    float* __restrict__ out)
{
    __shared__ __align__(16) unsigned s2[18436];   // 9217 cells x 2 words (+pad)
    const int tid = threadIdx.x;
    const int bid = blockIdx.x;
    const int b = bid & 3;

    if (tid < 4) s2[18432 + tid] = 0;              // zero cell (+pad)

    const uint4* tA = tabA + b * 9216;
    const unsigned short* tB = tabB + b * 9216;
    const int* idxb = idx + b * 9216;
    const f2 nv = {NINE_INV, NINE_INV};

    // inline fallback offset computation (cell index, ZCELL if invalid)
    auto inline_cells = [&](int u, unsigned* e) {
        int r = u / 96, t = u - 96 * r;
#pragma unroll
        for (int i = 0; i < 3; ++i) {
            int oy = r - 1 + i;
            bool oyv = (unsigned)oy < 96u;
#pragma unroll
            for (int j = 0; j < 3; ++j) {
                int ox = t - 1 + j;
                bool pv = oyv & ((unsigned)ox < 96u);
                int jv = idxb[pv ? oy * 96 + ox : 0];
                int jy = jv / 96, jx = jv - 96 * jy;
                int ysh = jy + 1 - i, xsh = jx + 1 - j;
                bool sv = pv & ((unsigned)ysh < 96u) & ((unsigned)xsh < 96u);
                e[i * 3 + j] = sv ? (unsigned)(ysh * 96 + xsh) : ZCELL;
            }
        }
    };

    auto do_taps = [&](const unsigned* cw, unsigned c8, f2& a0, f2& a1) {
#pragma unroll
        for (int q = 0; q < 4; ++q) {
            unsigned lo = cw[q] & 0xffffu, hi = cw[q] >> 16;
            uint2 wa = *(const uint2*)((const char*)s2 + (lo << 3));
            uint2 wb = *(const uint2*)((const char*)s2 + (hi << 3));
            a0 += up2(wa.x); a1 += up2(wa.y);
            a0 += up2(wb.x); a1 += up2(wb.y);
        }
        uint2 wc = *(const uint2*)((const char*)s2 + (c8 << 3));
        a0 += up2(wc.x); a1 += up2(wc.y);
    };

    if (bid < 256) {
        // ---------------- lv1: b, parity q, channel pair ----------------
        const int q = (bid >> 2) & 1, c0 = (bid >> 3) * 2;
        const float* g0 = ref1 + (size_t)(b * 64 + c0) * 36864;

        for (int u2 = tid; u2 < 4608; u2 += 512) {
            int ysh = u2 / 48, xsh0 = 2 * (u2 - 48 * ysh);
            const float* gp = g0 + (size_t)(2 * ysh + q) * 192 + 2 * xsh0;
            f4 va = ntload((const f4*)gp);            // ch0
            f4 vb = ntload((const f4*)(gp + 36864));  // ch1
            uint4 w;
            w.x = cvt_pk_bf16(va.x, va.y); w.y = cvt_pk_bf16(vb.x, vb.y);
            w.z = cvt_pk_bf16(va.z, va.w); w.w = cvt_pk_bf16(vb.z, vb.w);
            *(uint4*)(s2 + 4 * u2) = w;
        }
        __syncthreads();

        float* ob = out + 4718592 + (size_t)(b * 64 + c0) * 36864;

        uint4 cA; unsigned cB;
        if (TAB) { cA = tA[tid]; cB = tB[tid]; }
        int u = tid;
#pragma unroll 2
        for (int k = 0; k < 18; ++k) {
            uint4 nA = cA; unsigned nB = cB;
            if (TAB && k < 17) { nA = tA[u + 512]; nB = tB[u + 512]; }
            unsigned cw[4];
            unsigned c8;
            if (TAB) {
                cw[0] = cA.x; cw[1] = cA.y; cw[2] = cA.z; cw[3] = cA.w; c8 = cB;
            } else {
                unsigned e[9];
                inline_cells(u, e);
                cw[0] = e[0] | (e[1] << 16); cw[1] = e[2] | (e[3] << 16);
                cw[2] = e[4] | (e[5] << 16); cw[3] = e[6] | (e[7] << 16);
                c8 = e[8];
            }
            f2 a0 = {0.f, 0.f}, a1 = {0.f, 0.f};
            do_taps(cw, c8, a0, a1);
            a0 *= nv; a1 *= nv;
            int r = u / 96, t = u - 96 * r;
            float* op = ob + (size_t)(2 * r + q) * 192 + 2 * t;
            ntstore((f2*)op, a0);
            ntstore((f2*)(op + 36864), a1);
            u += 512; cA = nA; cB = nB;
        }
    } else {
        // ---------------- lv2: b, 4-ch group, position half ----------------
        const int r2 = bid - 256;
        const int grp = (r2 >> 2) & 31, h = (r2 >> 7) & 1;
        const int c0 = grp * 4;
        const float* g0 = ref2 + (size_t)(b * 128 + c0) * 9216;

        for (int u2 = tid; u2 < 4608; u2 += 512) {
            f2 p0 = ntload((const f2*)(g0 + 2 * u2));
            f2 p1 = ntload((const f2*)(g0 + 9216 + 2 * u2));
            f2 p2 = ntload((const f2*)(g0 + 2 * 9216 + 2 * u2));
            f2 p3 = ntload((const f2*)(g0 + 3 * 9216 + 2 * u2));
            uint4 w;
            w.x = cvt_pk_bf16(p0.x, p1.x); w.y = cvt_pk_bf16(p2.x, p3.x);
            w.z = cvt_pk_bf16(p0.y, p1.y); w.w = cvt_pk_bf16(p2.y, p3.y);
            *(uint4*)(s2 + 4 * u2) = w;
        }
        __syncthreads();

        float* ob = out + (size_t)(b * 128 + c0) * 9216;

        const int u0 = h * 4608;
        uint4 cA; unsigned cB;
        if (TAB) { cA = tA[u0 + tid]; cB = tB[u0 + tid]; }
        int u = u0 + tid;
#pragma unroll 2
        for (int k = 0; k < 9; ++k) {
            uint4 nA = cA; unsigned nB = cB;
            if (TAB && k < 8) { nA = tA[u + 512]; nB = tB[u + 512]; }
            unsigned cw[4];
            unsigned c8;
            if (TAB) {
                cw[0] = cA.x; cw[1] = cA.y; cw[2] = cA.z; cw[3] = cA.w; c8 = cB;
            } else {
                unsigned e[9];
                inline_cells(u, e);
                cw[0] = e[0] | (e[1] << 16); cw[1] = e[2] | (e[3] << 16);
                cw[2] = e[4] | (e[5] << 16); cw[3] = e[6] | (e[7] << 16);
                c8 = e[8];
            }
            f2 a0 = {0.f, 0.f}, a1 = {0.f, 0.f};
            do_taps(cw, c8, a0, a1);
            a0 *= nv; a1 *= nv;
            float* op = ob + u;
            ntstore(op, a0.x);            ntstore(op + 9216, a0.y);
            ntstore(op + 2 * 9216, a1.x); ntstore(op + 3 * 9216, a1.y);
            u += 512; cA = nA; cB = nB;
        }
    }
}

extern "C" void kernel_launch(void* const* d_in, const int* in_sizes, int n_in,
                              void* d_out, int out_size, void* d_ws, size_t ws_size,
                              hipStream_t stream) {
    const int*   idx  = (const int*)d_in[0];   // R_lv2_star_arg [4,9216]
    const float* ref1 = (const float*)d_in[2]; // ref_lv1 [4,64,192,192]
    const float* ref2 = (const float*)d_in[3]; // ref_lv2 [4,128,96,96]
    float* outp = (float*)d_out;

    uint4* tabA = (uint4*)d_ws;                          // 4*9216*16 B
    unsigned short* tabB = (unsigned short*)((char*)d_ws + (size_t)4 * 9216 * 16);

    const size_t need = (size_t)4 * 9216 * 16 + (size_t)4 * 9216 * 2;  // 664 KB
    if (ws_size >= need) {
        hipLaunchKernelGGL(table_kernel, dim3(144), dim3(256), 0, stream,
                           idx, tabA, tabB);
        hipLaunchKernelGGL(transfer_kernel<true>, dim3(512), dim3(512), 0, stream,
                           idx, ref1, ref2, tabA, tabB, outp);
    } else {
        hipLaunchKernelGGL(transfer_kernel<false>, dim3(512), dim3(512), 0, stream,
                           idx, ref1, ref2, tabA, tabB, outp);
    }
}